// Round 1
// baseline (236.273 us; speedup 1.0000x reference)
//
#include <hip/hip_runtime.h>

// DiagLRConv: out[n,o,h,w] = sum_{k=0..4} sum_{i=0..15} fw[o,i,k] * x[n,i,h+k-2,w+k-2]
// x: (16,16,512,512) fp32, fw: (16,16,5) fp32, out: (16,16,512,512) fp32.

#define HH   512
#define WW   512
#define CH   16   // channels (in == out)
#define KK   5
#define PX   4    // pixels per thread along w (stride 64)

__global__ __launch_bounds__(256, 2)
void diag_conv_kernel(const float* __restrict__ x,
                      const float* __restrict__ fw,
                      float* __restrict__ out)
{
    // Stage weights transposed to [k][o][i] for contiguous float4 broadcast reads.
    __shared__ __align__(16) float Wlds[KK][CH][CH];
    int tid = threadIdx.x;
    for (int idx = tid; idx < KK * CH * CH; idx += 256) {
        int k   = idx / (CH * CH);
        int rem = idx - k * CH * CH;
        int o   = rem >> 4;
        int i   = rem & 15;
        Wlds[k][o][i] = fw[(o * CH + i) * KK + k];
    }
    __syncthreads();

    const int wave  = tid >> 6;
    const int lane  = tid & 63;
    const int wt    = blockIdx.x;   // 0..1   (w tiles of 256)
    const int ht    = blockIdx.y;   // 0..127 (h tiles of 4 rows)
    const int n     = blockIdx.z;   // 0..15

    const int h     = ht * 4 + wave;
    const int wbase = wt * 256 + lane;

    const float* __restrict__ xn = x + (size_t)n * CH * HH * WW;

    float acc[CH][PX];
#pragma unroll
    for (int o = 0; o < CH; ++o)
#pragma unroll
        for (int p = 0; p < PX; ++p) acc[o][p] = 0.f;

#pragma unroll 1
    for (int k = 0; k < KK; ++k) {
        const int hh = h + k - 2;
        if ((unsigned)hh >= (unsigned)HH) continue;   // uniform per wave

        // Per-pixel w index + validity (clamped address, masked value).
        int  wwc[PX];
        bool wok[PX];
#pragma unroll
        for (int p = 0; p < PX; ++p) {
            int ww = wbase + 64 * p + k - 2;
            wok[p] = (unsigned)ww < (unsigned)WW;
            wwc[p] = wok[p] ? ww : 0;
        }

        // Load x fragment: 16 channels x PX pixels (coalesced dword loads).
        float xv[CH][PX];
        const float* __restrict__ xrow = xn + (size_t)hh * WW;
#pragma unroll
        for (int i = 0; i < CH; ++i) {
            const float* __restrict__ xr = xrow + (size_t)i * HH * WW;
#pragma unroll
            for (int p = 0; p < PX; ++p) {
                float v = xr[wwc[p]];
                xv[i][p] = wok[p] ? v : 0.f;
            }
        }

        // FMA block: 16 o x 16 i x PX, weights broadcast from LDS (float4).
#pragma unroll
        for (int o = 0; o < CH; ++o) {
            const float4* __restrict__ wrow =
                reinterpret_cast<const float4*>(&Wlds[k][o][0]);
            float4 wq0 = wrow[0];
            float4 wq1 = wrow[1];
            float4 wq2 = wrow[2];
            float4 wq3 = wrow[3];
#pragma unroll
            for (int p = 0; p < PX; ++p) {
                acc[o][p] = fmaf(wq0.x, xv[ 0][p], acc[o][p]);
                acc[o][p] = fmaf(wq0.y, xv[ 1][p], acc[o][p]);
                acc[o][p] = fmaf(wq0.z, xv[ 2][p], acc[o][p]);
                acc[o][p] = fmaf(wq0.w, xv[ 3][p], acc[o][p]);
                acc[o][p] = fmaf(wq1.x, xv[ 4][p], acc[o][p]);
                acc[o][p] = fmaf(wq1.y, xv[ 5][p], acc[o][p]);
                acc[o][p] = fmaf(wq1.z, xv[ 6][p], acc[o][p]);
                acc[o][p] = fmaf(wq1.w, xv[ 7][p], acc[o][p]);
                acc[o][p] = fmaf(wq2.x, xv[ 8][p], acc[o][p]);
                acc[o][p] = fmaf(wq2.y, xv[ 9][p], acc[o][p]);
                acc[o][p] = fmaf(wq2.z, xv[10][p], acc[o][p]);
                acc[o][p] = fmaf(wq2.w, xv[11][p], acc[o][p]);
                acc[o][p] = fmaf(wq3.x, xv[12][p], acc[o][p]);
                acc[o][p] = fmaf(wq3.y, xv[13][p], acc[o][p]);
                acc[o][p] = fmaf(wq3.z, xv[14][p], acc[o][p]);
                acc[o][p] = fmaf(wq3.w, xv[15][p], acc[o][p]);
            }
        }
    }

    // Store 16 o x PX pixels (coalesced dword stores).
    float* __restrict__ on = out + (size_t)n * CH * HH * WW + (size_t)h * WW;
#pragma unroll
    for (int o = 0; o < CH; ++o) {
#pragma unroll
        for (int p = 0; p < PX; ++p) {
            on[(size_t)o * HH * WW + wbase + 64 * p] = acc[o][p];
        }
    }
}

extern "C" void kernel_launch(void* const* d_in, const int* in_sizes, int n_in,
                              void* d_out, int out_size, void* d_ws, size_t ws_size,
                              hipStream_t stream)
{
    const float* x  = (const float*)d_in[0];
    const float* fw = (const float*)d_in[1];
    float* out      = (float*)d_out;

    dim3 grid(WW / 256, HH / 4, 16);  // (w tiles, h tiles, n)
    dim3 block(256);
    diag_conv_kernel<<<grid, block, 0, stream>>>(x, fw, out);
}